// Round 4
// baseline (159.464 us; speedup 1.0000x reference)
//
#include <hip/hip_runtime.h>
#include <hip/hip_bf16.h>
#include <math.h>

// Temporal attention: B=32, N=2048, F=16, T=64
//   y[b,t,f]   = sum_n U1[n] * x[b,n,f,t]
//   r[b,n,u]   = sum_f U3[f] * x[b,n,f,u]
//   z[b,f,u]   = sum_n U2[f,n] * r[b,n,u]
//   product[b,t,u] = sum_f y[b,t,f] * z[b,f,u]
//   E[b,t,u] = sum_s Ve[t,s] * sigmoid(product[b,s,u] + be[s,u])
//   out = softmax over t (axis=1)
//
// DIAGNOSTIC ROUND: pass 1 reads x NREAD=3 times with per-pass weights
// {0.25, 0.5, 0.25} folded into U1/U3 (sum == 1.0 exactly -> same result).
// Purpose: push pass 1 above the harness's ~155 us fill kernels so it
// surfaces in the rocprof top-5 with FETCH_SIZE / hbm_gbps / VALUBusy /
// OccupancyPercent. Also maxes occupancy (8 blocks/CU) to isolate that lever
// via per-read time = (dur - pass2) / 3.

#define B_ 32
#define N_ 2048
#define F_ 16
#define T_ 64
#define NPB 32               // n-rows per block in pass 1
#define CHUNKS (N_ / NPB)    // 64 chunks per batch
#define NREAD 3

// ---------------- Pass 1: block-linear stream of x, read 3x (diagnostic) ---
__global__ __launch_bounds__(256, 8) void ta_pass1(
    const float* __restrict__ x, const float* __restrict__ U1,
    const float* __restrict__ U2, const float* __restrict__ U3,
    float* __restrict__ partial)
{
  const int blk    = blockIdx.x;
  const int b      = blk >> 6;       // / CHUNKS
  const int chunk  = blk & 63;       // % CHUNKS
  const int n_base = chunk * NPB;
  const int tid    = threadIdx.x;
  const int lane   = tid & 63;
  const int w      = tid >> 6;
  const int g      = lane >> 4;      // 0..3 (f-group within wave)
  const int tq     = lane & 15;      // t-quad index

  __shared__ float4 u2q[NPB][4];     // u2q[n][g][c] = U2[(g+4c)*N + n]
  __shared__ float4 zred[4][256];    // per-wave z partials

  for (int i = tid; i < NPB * F_; i += 256) {   // coalesced over n
    const int f = i >> 5, n = i & 31;
    reinterpret_cast<float*>(&u2q[n][f & 3])[f >> 2] = U2[f * N_ + n_base + n];
  }
  const float u3own = U3[tid >> 4];
  __syncthreads();

  float4 ya  = make_float4(0.f, 0.f, 0.f, 0.f);
  float4 za0 = ya, za1 = ya, za2 = ya, za3 = ya;   // za[c] <-> f = g + 4c

  const float4* xb = reinterpret_cast<const float4*>(x)
                   + ((size_t)b * N_ + n_base) * 256;
  const float wtab[NREAD] = {0.25f, 0.5f, 0.25f};  // sums to exactly 1.0

  for (int k = 0; k < NREAD; ++k) {
    const float wk  = wtab[k];
    const float u3k = u3own * wk;
    #pragma unroll 4
    for (int n = 0; n < NPB; ++n) {
      const float4 v   = xb[n * 256 + tid];       // block-contiguous 4 KB/row
      const float  u1w = U1[n_base + n] * wk;     // uniform -> scalar
      ya.x = fmaf(u1w, v.x, ya.x);
      ya.y = fmaf(u1w, v.y, ya.y);
      ya.z = fmaf(u1w, v.z, ya.z);
      ya.w = fmaf(u1w, v.w, ya.w);
      // weighted r partial for own f, reduce over the wave's 4 f-groups
      float4 rp;
      rp.x = u3k * v.x; rp.y = u3k * v.y;
      rp.z = u3k * v.z; rp.w = u3k * v.w;
      rp.x += __shfl_xor(rp.x, 16); rp.y += __shfl_xor(rp.y, 16);
      rp.z += __shfl_xor(rp.z, 16); rp.w += __shfl_xor(rp.w, 16);
      rp.x += __shfl_xor(rp.x, 32); rp.y += __shfl_xor(rp.y, 32);
      rp.z += __shfl_xor(rp.z, 32); rp.w += __shfl_xor(rp.w, 32);
      // online U2 projection: za[c] += U2[g+4c][n] * r (wave-partial)
      const float4 u2v = u2q[n][g];
      za0.x = fmaf(u2v.x, rp.x, za0.x); za0.y = fmaf(u2v.x, rp.y, za0.y);
      za0.z = fmaf(u2v.x, rp.z, za0.z); za0.w = fmaf(u2v.x, rp.w, za0.w);
      za1.x = fmaf(u2v.y, rp.x, za1.x); za1.y = fmaf(u2v.y, rp.y, za1.y);
      za1.z = fmaf(u2v.y, rp.z, za1.z); za1.w = fmaf(u2v.y, rp.w, za1.w);
      za2.x = fmaf(u2v.z, rp.x, za2.x); za2.y = fmaf(u2v.z, rp.y, za2.y);
      za2.z = fmaf(u2v.z, rp.z, za2.z); za2.w = fmaf(u2v.z, rp.w, za2.w);
      za3.x = fmaf(u2v.w, rp.x, za3.x); za3.y = fmaf(u2v.w, rp.y, za3.y);
      za3.z = fmaf(u2v.w, rp.z, za3.z); za3.w = fmaf(u2v.w, rp.w, za3.w);
    }
  }

  // z partials to LDS: zred[w][f*16 + tq], f = g + 4c
  zred[w][(g +  0) * 16 + tq] = za0;
  zred[w][(g +  4) * 16 + tq] = za1;
  zred[w][(g +  8) * 16 + tq] = za2;
  zred[w][(g + 12) * 16 + tq] = za3;
  __syncthreads();

  float4* pb = reinterpret_cast<float4*>(partial + (size_t)blk * 2048);
  pb[tid] = ya;                                   // y: float offset f*64 + t
  const float4 a0 = zred[0][tid], a1 = zred[1][tid];
  const float4 a2 = zred[2][tid], a3 = zred[3][tid];
  float4 zv;
  zv.x = a0.x + a1.x + a2.x + a3.x;
  zv.y = a0.y + a1.y + a2.y + a3.y;
  zv.z = a0.z + a1.z + a2.z + a3.z;
  zv.w = a0.w + a1.w + a2.w + a3.w;
  pb[256 + tid] = zv;                             // z: 1024 + f*64 + u
}

// ---------------- Pass 2: reduce partials, product+sigmoid, Ve, softmax ----
__global__ __launch_bounds__(256) void ta_finish(
    const float* __restrict__ partial, const float* __restrict__ be,
    const float* __restrict__ Ve, float* __restrict__ out)
{
  const int b   = blockIdx.x;
  const int tid = threadIdx.x;
  __shared__ float ys[T_][F_ + 1];
  __shared__ float zs[F_][T_];
  __shared__ float sig[T_][T_ + 1];
  __shared__ float Es[T_][T_ + 1];

  // reduce the CHUNKS partials for this batch (float4)
  const float4* p4 = reinterpret_cast<const float4*>(partial) + (size_t)b * CHUNKS * 512;
  #pragma unroll
  for (int k = 0; k < 2; ++k) {
    const int i4 = tid + k * 256;
    float4 s = make_float4(0.f, 0.f, 0.f, 0.f);
    #pragma unroll 4
    for (int j = 0; j < CHUNKS; ++j) {
      const float4 v = p4[(size_t)j * 512 + i4];
      s.x += v.x; s.y += v.y; s.z += v.z; s.w += v.w;
    }
    if (i4 < 256) {
      const int f = i4 >> 4, t0 = (i4 & 15) * 4;
      ys[t0 + 0][f] = s.x; ys[t0 + 1][f] = s.y;
      ys[t0 + 2][f] = s.z; ys[t0 + 3][f] = s.w;
    } else {
      const int j4 = i4 - 256;
      const int f = j4 >> 4, u0 = (j4 & 15) * 4;
      zs[f][u0 + 0] = s.x; zs[f][u0 + 1] = s.y;
      zs[f][u0 + 2] = s.z; zs[f][u0 + 3] = s.w;
    }
  }
  __syncthreads();

  const int tr = tid >> 2;          // row 0..63
  const int ub = (tid & 3) * 16;    // 16-wide u slab
  #pragma unroll
  for (int i = 0; i < 16; ++i) {
    const int u = ub + i;
    float acc = 0.f;
    #pragma unroll
    for (int f = 0; f < F_; ++f) acc = fmaf(ys[tr][f], zs[f][u], acc);
    acc += be[tr * T_ + u];
    sig[tr][u] = 1.f / (1.f + __expf(-acc));
  }
  __syncthreads();
  #pragma unroll
  for (int i = 0; i < 16; ++i) {
    const int u = ub + i;
    float acc = 0.f;
    #pragma unroll
    for (int s = 0; s < T_; ++s) acc = fmaf(Ve[tr * T_ + s], sig[s][u], acc);
    Es[tr][u] = acc;
  }
  __syncthreads();

  // softmax over t (axis=1): 4 threads per column u, 16 rows each
  const int u = tid >> 2, p = tid & 3;
  float m = -INFINITY;
  #pragma unroll
  for (int r = 0; r < 16; ++r) m = fmaxf(m, Es[p * 16 + r][u]);
  m = fmaxf(m, __shfl_xor(m, 1));
  m = fmaxf(m, __shfl_xor(m, 2));
  float den = 0.f;
  #pragma unroll
  for (int r = 0; r < 16; ++r) den += __expf(Es[p * 16 + r][u] - m);
  den += __shfl_xor(den, 1);
  den += __shfl_xor(den, 2);
  const float inv = 1.f / den;
  #pragma unroll
  for (int r = 0; r < 16; ++r)
    out[(size_t)b * T_ * T_ + (p * 16 + r) * T_ + u] =
        __expf(Es[p * 16 + r][u] - m) * inv;
}

extern "C" void kernel_launch(void* const* d_in, const int* in_sizes, int n_in,
                              void* d_out, int out_size, void* d_ws, size_t ws_size,
                              hipStream_t stream) {
  const float* x  = (const float*)d_in[0];
  const float* U1 = (const float*)d_in[1];
  const float* U2 = (const float*)d_in[2];
  const float* U3 = (const float*)d_in[3];
  const float* be = (const float*)d_in[4];
  const float* Ve = (const float*)d_in[5];
  float* out = (float*)d_out;
  float* partial = (float*)d_ws;   // B_*CHUNKS*2048*4 = 16 MB of scratch

  ta_pass1<<<B_ * CHUNKS, 256, 0, stream>>>(x, U1, U2, U3, partial);
  ta_finish<<<B_, 256, 0, stream>>>(partial, be, Ve, out);
}

// Round 5
// 86.496 us; speedup vs baseline: 1.8436x; 1.8436x over previous
//
#include <hip/hip_runtime.h>
#include <hip/hip_bf16.h>
#include <math.h>

// Temporal attention: B=32, N=2048, F=16, T=64
//   y[b,t,f]   = sum_n U1[n] * x[b,n,f,t]
//   r[b,n,u]   = sum_f U3[f] * x[b,n,f,u]
//   z[b,f,u]   = sum_n U2[f,n] * r[b,n,u]
//   product[b,t,u] = sum_f y[b,t,f] * z[b,f,u]
//   E[b,t,u] = sum_s Ve[t,s] * sigmoid(product[b,s,u] + be[s,u])
//   out = softmax over t (axis=1)
//
// Pass 1 is a global_load_lds DMA pipeline: 3 LDS slots x 16KB (4 rows),
// counted s_waitcnt vmcnt(4), raw s_barrier (no __syncthreads in the loop).
// Loads never target VGPRs, so compute dependencies cannot stall the stream.

#define B_ 32
#define N_ 2048
#define F_ 16
#define T_ 64
#define NPB 32               // n-rows per block in pass 1
#define CHUNKS (N_ / NPB)    // 64 chunks per batch
#define TR 4                 // rows per tile (16 KB)
#define NT (NPB / TR)        // 8 tiles per block
#define SLOTS 3

__global__ __launch_bounds__(256, 3) void ta_pass1(
    const float* __restrict__ x, const float* __restrict__ U1,
    const float* __restrict__ U2, const float* __restrict__ U3,
    float* __restrict__ partial)
{
  const int blk    = blockIdx.x;
  const int b      = blk >> 6;       // / CHUNKS
  const int chunk  = blk & 63;       // % CHUNKS
  const int n_base = chunk * NPB;
  const int tid    = threadIdx.x;
  const int lane   = tid & 63;
  const int w      = tid >> 6;       // wave id (uniform per wave)
  const int g      = lane >> 4;      // 0..3 f-group within wave
  const int tq     = lane & 15;      // t-quad index

  __shared__ float4 slots[SLOTS * 1024];   // 48 KB tile pipeline (reused as zred)
  __shared__ float4 u2q[NPB][4];           // u2q[n][g][c] = U2[(g+4c)*N + n]
  __shared__ float  u1s[NPB];

  // ---- prologue: parameter staging, then issue tiles 0,1 ----
  const float u3own = U3[tid >> 4];
  const int f0 = tid >> 5, n0 = tid & 31;
  const int f1 = (tid + 256) >> 5;
  const float u2a = U2[f0 * N_ + n_base + n0];
  const float u2b = U2[f1 * N_ + n_base + n0];
  float u1v = 0.f;
  if (tid < NPB) u1v = U1[n_base + tid];

  reinterpret_cast<float*>(&u2q[n0][f0 & 3])[f0 >> 2] = u2a;
  reinterpret_cast<float*>(&u2q[n0][f1 & 3])[f1 >> 2] = u2b;
  if (tid < NPB) u1s[tid] = u1v;

  const char* xb = reinterpret_cast<const char*>(x)
                 + ((size_t)b * N_ + n_base) * 4096;   // 4 KB per row

  auto stage_tile = [&](int t) {
    const char* gsrc = xb + (size_t)t * 16384 + w * 4096 + lane * 16;  // per-lane
    char* ldst = reinterpret_cast<char*>(slots)
               + (t % SLOTS) * 16384 + w * 4096;                       // wave-uniform
    #pragma unroll
    for (int i = 0; i < 4; ++i) {
      __builtin_amdgcn_global_load_lds(
          (const __attribute__((address_space(1))) void*)(gsrc + i * 1024),
          (__attribute__((address_space(3))) void*)(ldst + i * 1024),
          16, 0, 0);
    }
  };

  stage_tile(0);
  stage_tile(1);
  asm volatile("s_waitcnt lgkmcnt(0)" ::: "memory");
  __builtin_amdgcn_s_barrier();

  float4 ya  = make_float4(0.f, 0.f, 0.f, 0.f);
  float4 za0 = ya, za1 = ya, za2 = ya, za3 = ya;   // za[c] <-> f = g + 4c

  // ---- main pipeline ----
  for (int t = 0; t < NT; ++t) {
    if (t == NT - 1) { asm volatile("s_waitcnt vmcnt(0)" ::: "memory"); }
    else             { asm volatile("s_waitcnt vmcnt(4)" ::: "memory"); }
    __builtin_amdgcn_s_barrier();          // tile t fully landed (all waves)
    if (t + 2 < NT) stage_tile(t + 2);     // slot (t+2)%3 freed at this barrier

    const float4* sl = slots + (t % SLOTS) * 1024;
    #pragma unroll
    for (int n = 0; n < TR; ++n) {
      const float4 v  = sl[n * 256 + tid];           // ds_read_b128
      const float  u1 = u1s[t * TR + n];
      ya.x = fmaf(u1, v.x, ya.x);
      ya.y = fmaf(u1, v.y, ya.y);
      ya.z = fmaf(u1, v.z, ya.z);
      ya.w = fmaf(u1, v.w, ya.w);
      float4 rp;
      rp.x = u3own * v.x; rp.y = u3own * v.y;
      rp.z = u3own * v.z; rp.w = u3own * v.w;
      rp.x += __shfl_xor(rp.x, 16); rp.y += __shfl_xor(rp.y, 16);
      rp.z += __shfl_xor(rp.z, 16); rp.w += __shfl_xor(rp.w, 16);
      rp.x += __shfl_xor(rp.x, 32); rp.y += __shfl_xor(rp.y, 32);
      rp.z += __shfl_xor(rp.z, 32); rp.w += __shfl_xor(rp.w, 32);
      const float4 u2v = u2q[t * TR + n][g];
      za0.x = fmaf(u2v.x, rp.x, za0.x); za0.y = fmaf(u2v.x, rp.y, za0.y);
      za0.z = fmaf(u2v.x, rp.z, za0.z); za0.w = fmaf(u2v.x, rp.w, za0.w);
      za1.x = fmaf(u2v.y, rp.x, za1.x); za1.y = fmaf(u2v.y, rp.y, za1.y);
      za1.z = fmaf(u2v.y, rp.z, za1.z); za1.w = fmaf(u2v.y, rp.w, za1.w);
      za2.x = fmaf(u2v.z, rp.x, za2.x); za2.y = fmaf(u2v.z, rp.y, za2.y);
      za2.z = fmaf(u2v.z, rp.z, za2.z); za2.w = fmaf(u2v.z, rp.w, za2.w);
      za3.x = fmaf(u2v.w, rp.x, za3.x); za3.y = fmaf(u2v.w, rp.y, za3.y);
      za3.z = fmaf(u2v.w, rp.z, za3.z); za3.w = fmaf(u2v.w, rp.w, za3.w);
    }
    asm volatile("s_waitcnt lgkmcnt(0)" ::: "memory");  // slot reads complete
  }

  // ---- epilogue: reuse slot LDS for the cross-wave z reduction ----
  __syncthreads();
  float4* zred = slots;                    // [w][256]
  zred[w * 256 + (g +  0) * 16 + tq] = za0;
  zred[w * 256 + (g +  4) * 16 + tq] = za1;
  zred[w * 256 + (g +  8) * 16 + tq] = za2;
  zred[w * 256 + (g + 12) * 16 + tq] = za3;
  __syncthreads();

  float4* pb = reinterpret_cast<float4*>(partial + (size_t)blk * 2048);
  pb[tid] = ya;                            // y: float offset f*64 + t
  const float4 a0 = zred[0 * 256 + tid], a1 = zred[1 * 256 + tid];
  const float4 a2 = zred[2 * 256 + tid], a3 = zred[3 * 256 + tid];
  float4 zv;
  zv.x = a0.x + a1.x + a2.x + a3.x;
  zv.y = a0.y + a1.y + a2.y + a3.y;
  zv.z = a0.z + a1.z + a2.z + a3.z;
  zv.w = a0.w + a1.w + a2.w + a3.w;
  pb[256 + tid] = zv;                      // z: 1024 + f*64 + u
}

// ---------------- Pass 2: reduce partials, product+sigmoid, Ve, softmax ----
__global__ __launch_bounds__(256) void ta_finish(
    const float* __restrict__ partial, const float* __restrict__ be,
    const float* __restrict__ Ve, float* __restrict__ out)
{
  const int b   = blockIdx.x;
  const int tid = threadIdx.x;
  __shared__ float ys[T_][F_ + 1];
  __shared__ float zs[F_][T_];
  __shared__ float sig[T_][T_ + 1];
  __shared__ float Es[T_][T_ + 1];

  // reduce the CHUNKS partials for this batch (float4)
  const float4* p4 = reinterpret_cast<const float4*>(partial) + (size_t)b * CHUNKS * 512;
  #pragma unroll
  for (int k = 0; k < 2; ++k) {
    const int i4 = tid + k * 256;
    float4 s = make_float4(0.f, 0.f, 0.f, 0.f);
    #pragma unroll 8
    for (int j = 0; j < CHUNKS; ++j) {
      const float4 v = p4[(size_t)j * 512 + i4];
      s.x += v.x; s.y += v.y; s.z += v.z; s.w += v.w;
    }
    if (i4 < 256) {
      const int f = i4 >> 4, t0 = (i4 & 15) * 4;
      ys[t0 + 0][f] = s.x; ys[t0 + 1][f] = s.y;
      ys[t0 + 2][f] = s.z; ys[t0 + 3][f] = s.w;
    } else {
      const int j4 = i4 - 256;
      const int f = j4 >> 4, u0 = (j4 & 15) * 4;
      zs[f][u0 + 0] = s.x; zs[f][u0 + 1] = s.y;
      zs[f][u0 + 2] = s.z; zs[f][u0 + 3] = s.w;
    }
  }
  __syncthreads();

  const int tr = tid >> 2;          // row 0..63
  const int ub = (tid & 3) * 16;    // 16-wide u slab
  #pragma unroll
  for (int i = 0; i < 16; ++i) {
    const int u = ub + i;
    float acc = 0.f;
    #pragma unroll
    for (int f = 0; f < F_; ++f) acc = fmaf(ys[tr][f], zs[f][u], acc);
    acc += be[tr * T_ + u];
    sig[tr][u] = 1.f / (1.f + __expf(-acc));
  }
  __syncthreads();
  #pragma unroll
  for (int i = 0; i < 16; ++i) {
    const int u = ub + i;
    float acc = 0.f;
    #pragma unroll
    for (int s = 0; s < T_; ++s) acc = fmaf(Ve[tr * T_ + s], sig[s][u], acc);
    Es[tr][u] = acc;
  }
  __syncthreads();

  // softmax over t (axis=1): 4 threads per column u, 16 rows each
  const int u = tid >> 2, p = tid & 3;
  float m = -INFINITY;
  #pragma unroll
  for (int r = 0; r < 16; ++r) m = fmaxf(m, Es[p * 16 + r][u]);
  m = fmaxf(m, __shfl_xor(m, 1));
  m = fmaxf(m, __shfl_xor(m, 2));
  float den = 0.f;
  #pragma unroll
  for (int r = 0; r < 16; ++r) den += __expf(Es[p * 16 + r][u] - m);
  den += __shfl_xor(den, 1);
  den += __shfl_xor(den, 2);
  const float inv = 1.f / den;
  #pragma unroll
  for (int r = 0; r < 16; ++r)
    out[(size_t)b * T_ * T_ + (p * 16 + r) * T_ + u] =
        __expf(Es[p * 16 + r][u] - m) * inv;
}

extern "C" void kernel_launch(void* const* d_in, const int* in_sizes, int n_in,
                              void* d_out, int out_size, void* d_ws, size_t ws_size,
                              hipStream_t stream) {
  const float* x  = (const float*)d_in[0];
  const float* U1 = (const float*)d_in[1];
  const float* U2 = (const float*)d_in[2];
  const float* U3 = (const float*)d_in[3];
  const float* be = (const float*)d_in[4];
  const float* Ve = (const float*)d_in[5];
  float* out = (float*)d_out;
  float* partial = (float*)d_ws;   // B_*CHUNKS*2048*4 = 16 MB of scratch

  ta_pass1<<<B_ * CHUNKS, 256, 0, stream>>>(x, U1, U2, U3, partial);
  ta_finish<<<B_, 256, 0, stream>>>(partial, be, Ve, out);
}

// Round 7
// 73.368 us; speedup vs baseline: 2.1735x; 1.1789x over previous
//
#include <hip/hip_runtime.h>
#include <hip/hip_bf16.h>
#include <math.h>

// Temporal attention: B=32, N=2048, F=16, T=64
//   y[b,t,f]   = sum_n U1[n] * x[b,n,f,t]
//   r[b,n,u]   = sum_f U3[f] * x[b,n,f,u]
//   z[b,f,u]   = sum_n U2[f,n] * r[b,n,u]
//   product[b,t,u] = sum_f y[b,t,f] * z[b,f,u]
//   E[b,t,u] = sum_s Ve[t,s] * sigmoid(product[b,s,u] + be[s,u])
//   out = softmax over t (axis=1)
//
// R6 = R5 with the nontemporal builtin applied to a native clang vector type
// (ext_vector_type(4)) instead of HIP_vector_type, which the builtin rejects.
// NPB=128 (partial = 4 MB), non-temporal partial I/O (protect x's L3
// residency), unroll-8 hot loop with VGPR headroom (2 blocks/CU).

#define B_ 32
#define N_ 2048
#define F_ 16
#define T_ 64
#define NPB 128              // n-rows per block in pass 1
#define CHUNKS (N_ / NPB)    // 16 chunks per batch

typedef float f32x4 __attribute__((ext_vector_type(4)));

// ---------------- Pass 1: block-linear stream of x, one row per iteration --
// Row (b,n) = F*T*4 = 4096 B = 256 threads x float4. Thread tid owns
// (f = tid>>4, t-quad = tid&15) of every row.
__global__ __launch_bounds__(256, 2) void ta_pass1(
    const float* __restrict__ x, const float* __restrict__ U1,
    const float* __restrict__ U2, const float* __restrict__ U3,
    float* __restrict__ partial)
{
  const int blk    = blockIdx.x;
  const int b      = blk >> 4;       // / CHUNKS
  const int chunk  = blk & 15;       // % CHUNKS
  const int n_base = chunk * NPB;
  const int tid    = threadIdx.x;
  const int lane   = tid & 63;
  const int w      = tid >> 6;
  const int g      = lane >> 4;      // 0..3 (f-group within wave)
  const int tq     = lane & 15;      // t-quad index

  __shared__ float4 u2q[NPB][4];     // u2q[n][g][c] = U2[(g+4c)*N + n]  (8 KB)
  __shared__ float4 zred[4][256];    // per-wave z partials (16 KB)

  for (int i = tid; i < NPB * F_; i += 256) {   // coalesced over n
    const int f = i >> 7, n = i & (NPB - 1);
    reinterpret_cast<float*>(&u2q[n][f & 3])[f >> 2] = U2[f * N_ + n_base + n];
  }
  const float u3own = U3[tid >> 4];
  __syncthreads();

  float4 ya  = make_float4(0.f, 0.f, 0.f, 0.f);
  float4 za0 = ya, za1 = ya, za2 = ya, za3 = ya;   // za[c] <-> f = g + 4c

  const float4* xb = reinterpret_cast<const float4*>(x)
                   + ((size_t)b * N_ + n_base) * 256;
  #pragma unroll 8
  for (int n = 0; n < NPB; ++n) {
    const float4 v  = xb[n * 256 + tid];          // block-contiguous 4 KB/row
    const float  u1 = U1[n_base + n];             // uniform -> scalar load
    ya.x = fmaf(u1, v.x, ya.x);
    ya.y = fmaf(u1, v.y, ya.y);
    ya.z = fmaf(u1, v.z, ya.z);
    ya.w = fmaf(u1, v.w, ya.w);
    // r partial for own f, then reduce over the wave's 4 f-groups
    float4 rp;
    rp.x = u3own * v.x; rp.y = u3own * v.y;
    rp.z = u3own * v.z; rp.w = u3own * v.w;
    rp.x += __shfl_xor(rp.x, 16); rp.y += __shfl_xor(rp.y, 16);
    rp.z += __shfl_xor(rp.z, 16); rp.w += __shfl_xor(rp.w, 16);
    rp.x += __shfl_xor(rp.x, 32); rp.y += __shfl_xor(rp.y, 32);
    rp.z += __shfl_xor(rp.z, 32); rp.w += __shfl_xor(rp.w, 32);
    // online U2 projection: za[c] += U2[g+4c][n] * r (wave-partial)
    const float4 u2v = u2q[n][g];
    za0.x = fmaf(u2v.x, rp.x, za0.x); za0.y = fmaf(u2v.x, rp.y, za0.y);
    za0.z = fmaf(u2v.x, rp.z, za0.z); za0.w = fmaf(u2v.x, rp.w, za0.w);
    za1.x = fmaf(u2v.y, rp.x, za1.x); za1.y = fmaf(u2v.y, rp.y, za1.y);
    za1.z = fmaf(u2v.y, rp.z, za1.z); za1.w = fmaf(u2v.y, rp.w, za1.w);
    za2.x = fmaf(u2v.z, rp.x, za2.x); za2.y = fmaf(u2v.z, rp.y, za2.y);
    za2.z = fmaf(u2v.z, rp.z, za2.z); za2.w = fmaf(u2v.z, rp.w, za2.w);
    za3.x = fmaf(u2v.w, rp.x, za3.x); za3.y = fmaf(u2v.w, rp.y, za3.y);
    za3.z = fmaf(u2v.w, rp.z, za3.z); za3.w = fmaf(u2v.w, rp.w, za3.w);
  }

  // z partials to LDS: zred[w][f*16 + tq], f = g + 4c
  zred[w][(g +  0) * 16 + tq] = za0;
  zred[w][(g +  4) * 16 + tq] = za1;
  zred[w][(g +  8) * 16 + tq] = za2;
  zred[w][(g + 12) * 16 + tq] = za3;
  __syncthreads();

  // Non-temporal partial I/O: keep the scratch stream out of L3 so it does
  // not evict x (x is exactly L3-sized).
  f32x4* pb = reinterpret_cast<f32x4*>(partial + (size_t)blk * 2048);
  f32x4 yv;
  yv.x = ya.x; yv.y = ya.y; yv.z = ya.z; yv.w = ya.w;
  __builtin_nontemporal_store(yv, pb + tid);      // y: float offset f*64 + t
  const float4 a0 = zred[0][tid], a1 = zred[1][tid];
  const float4 a2 = zred[2][tid], a3 = zred[3][tid];
  f32x4 zv;
  zv.x = a0.x + a1.x + a2.x + a3.x;
  zv.y = a0.y + a1.y + a2.y + a3.y;
  zv.z = a0.z + a1.z + a2.z + a3.z;
  zv.w = a0.w + a1.w + a2.w + a3.w;
  __builtin_nontemporal_store(zv, pb + 256 + tid); // z: 1024 + f*64 + u
}

// ---------------- Pass 2: reduce partials, product+sigmoid, Ve, softmax ----
__global__ __launch_bounds__(256) void ta_finish(
    const float* __restrict__ partial, const float* __restrict__ be,
    const float* __restrict__ Ve, float* __restrict__ out)
{
  const int b   = blockIdx.x;
  const int tid = threadIdx.x;
  __shared__ float ys[T_][F_ + 1];
  __shared__ float zs[F_][T_];
  __shared__ float sig[T_][T_ + 1];
  __shared__ float Es[T_][T_ + 1];

  // reduce the CHUNKS partials for this batch (float4, non-temporal)
  const f32x4* p4 = reinterpret_cast<const f32x4*>(partial) + (size_t)b * CHUNKS * 512;
  #pragma unroll
  for (int k = 0; k < 2; ++k) {
    const int i4 = tid + k * 256;
    f32x4 s = (f32x4)(0.f);
    #pragma unroll 8
    for (int j = 0; j < CHUNKS; ++j) {
      const f32x4 v = __builtin_nontemporal_load(p4 + (size_t)j * 512 + i4);
      s += v;
    }
    if (i4 < 256) {
      const int f = i4 >> 4, t0 = (i4 & 15) * 4;
      ys[t0 + 0][f] = s.x; ys[t0 + 1][f] = s.y;
      ys[t0 + 2][f] = s.z; ys[t0 + 3][f] = s.w;
    } else {
      const int j4 = i4 - 256;
      const int f = j4 >> 4, u0 = (j4 & 15) * 4;
      zs[f][u0 + 0] = s.x; zs[f][u0 + 1] = s.y;
      zs[f][u0 + 2] = s.z; zs[f][u0 + 3] = s.w;
    }
  }
  __syncthreads();

  const int tr = tid >> 2;          // row 0..63
  const int ub = (tid & 3) * 16;    // 16-wide u slab
  #pragma unroll
  for (int i = 0; i < 16; ++i) {
    const int u = ub + i;
    float acc = 0.f;
    #pragma unroll
    for (int f = 0; f < F_; ++f) acc = fmaf(ys[tr][f], zs[f][u], acc);
    acc += be[tr * T_ + u];
    sig[tr][u] = 1.f / (1.f + __expf(-acc));
  }
  __syncthreads();
  #pragma unroll
  for (int i = 0; i < 16; ++i) {
    const int u = ub + i;
    float acc = 0.f;
    #pragma unroll
    for (int s = 0; s < T_; ++s) acc = fmaf(Ve[tr * T_ + s], sig[s][u], acc);
    Es[tr][u] = acc;
  }
  __syncthreads();

  // softmax over t (axis=1): 4 threads per column u, 16 rows each
  const int u = tid >> 2, p = tid & 3;
  float m = -INFINITY;
  #pragma unroll
  for (int r = 0; r < 16; ++r) m = fmaxf(m, Es[p * 16 + r][u]);
  m = fmaxf(m, __shfl_xor(m, 1));
  m = fmaxf(m, __shfl_xor(m, 2));
  float den = 0.f;
  #pragma unroll
  for (int r = 0; r < 16; ++r) den += __expf(Es[p * 16 + r][u] - m);
  den += __shfl_xor(den, 1);
  den += __shfl_xor(den, 2);
  const float inv = 1.f / den;
  #pragma unroll
  for (int r = 0; r < 16; ++r)
    out[(size_t)b * T_ * T_ + (p * 16 + r) * T_ + u] =
        __expf(Es[p * 16 + r][u] - m) * inv;
}

extern "C" void kernel_launch(void* const* d_in, const int* in_sizes, int n_in,
                              void* d_out, int out_size, void* d_ws, size_t ws_size,
                              hipStream_t stream) {
  const float* x  = (const float*)d_in[0];
  const float* U1 = (const float*)d_in[1];
  const float* U2 = (const float*)d_in[2];
  const float* U3 = (const float*)d_in[3];
  const float* be = (const float*)d_in[4];
  const float* Ve = (const float*)d_in[5];
  float* out = (float*)d_out;
  float* partial = (float*)d_ws;   // B_*CHUNKS*2048*4 = 4 MB of scratch

  ta_pass1<<<B_ * CHUNKS, 256, 0, stream>>>(x, U1, U2, U3, partial);
  ta_finish<<<B_, 256, 0, stream>>>(partial, be, Ve, out);
}